// Round 2
// baseline (2994.985 us; speedup 1.0000x reference)
//
#include <hip/hip_runtime.h>
#include <math.h>

#define NODES 100000
#define EDGES 1200000
#define NG 256

// ---------------- utility ----------------
__device__ __forceinline__ float wsum64(float v){
  v += __shfl_xor(v, 32); v += __shfl_xor(v, 16); v += __shfl_xor(v, 8);
  v += __shfl_xor(v, 4);  v += __shfl_xor(v, 2);  v += __shfl_xor(v, 1);
  return v;
}

__device__ __forceinline__ float blockSum128(float v, float* red){
  v = wsum64(v);
  if ((threadIdx.x & 63) == 0) red[threadIdx.x >> 6] = v;
  __syncthreads();
  float r = red[0] + red[1];
  __syncthreads();
  return r;
}

__global__ void k_zero_i(int* p, int n){ int i = blockIdx.x*256 + threadIdx.x; if (i < n) p[i] = 0; }
__global__ void k_zero_f(float* p, int n){ int i = blockIdx.x*256 + threadIdx.x; if (i < n) p[i] = 0.f; }

// ---------------- CSR build ----------------
__global__ void k_hist(const int* __restrict__ dst, int* __restrict__ counts){
  int e = blockIdx.x*256 + threadIdx.x;
  if (e < EDGES) atomicAdd(&counts[dst[e]], 1);
}

__global__ void k_scan1(const int* __restrict__ counts, int* __restrict__ rowptr, int* __restrict__ bsums){
  __shared__ int sd[256];
  int tid = threadIdx.x;
  int base = blockIdx.x*2048 + tid*8;
  int v[8]; int s = 0;
  #pragma unroll
  for (int i = 0; i < 8; i++){
    int idx = base + i;
    int c = (idx < NODES) ? counts[idx] : 0;
    v[i] = s; s += c;
  }
  sd[tid] = s;
  __syncthreads();
  for (int off = 1; off < 256; off <<= 1){
    int t = 0;
    if (tid >= off) t = sd[tid - off];
    __syncthreads();
    if (tid >= off) sd[tid] += t;
    __syncthreads();
  }
  int excl = (tid > 0) ? sd[tid-1] : 0;
  #pragma unroll
  for (int i = 0; i < 8; i++){
    int idx = base + i;
    if (idx < NODES) rowptr[idx] = v[i] + excl;
  }
  if (tid == 255) bsums[blockIdx.x] = sd[255];
}

__global__ void k_scan2(const int* __restrict__ bsums, int* __restrict__ boffs, int nb){
  if (threadIdx.x == 0 && blockIdx.x == 0){
    int run = 0;
    for (int b = 0; b < nb; b++){ boffs[b] = run; run += bsums[b]; }
  }
}

__global__ void k_scan3(int* __restrict__ rowptr, int* __restrict__ cursor, const int* __restrict__ boffs){
  int i = blockIdx.x*256 + threadIdx.x;
  if (i < NODES){
    int r = rowptr[i] + boffs[i >> 11];
    rowptr[i] = r; cursor[i] = r;
  }
  if (i == 0) rowptr[NODES] = EDGES;
}

__global__ void k_scatter(const int* __restrict__ src, const int* __restrict__ dst,
                          int* __restrict__ cursor, int* __restrict__ esrc){
  int e = blockIdx.x*256 + threadIdx.x;
  if (e < EDGES){
    int d = dst[e];
    int p = atomicAdd(&cursor[d], 1);
    esrc[p] = src[e];
  }
}

// ---------------- encoder: h = x@W+b ; z = relu(LN(h)) ----------------
__global__ __launch_bounds__(256) void k_enc(const float* __restrict__ x,
    const float* __restrict__ encW, const float* __restrict__ encb,
    const float* __restrict__ lg, const float* __restrict__ lb,
    float* __restrict__ h, float* __restrict__ z){
  __shared__ float we[320], wb[64], sg[64], sb[64];
  int tid = threadIdx.x;
  for (int i = tid; i < 320; i += 256) we[i] = encW[i];   // FIX: was `if (tid<320)` with 256 threads
  if (tid < 64){ wb[tid] = encb[tid]; sg[tid] = lg[tid]; sb[tid] = lb[tid]; }
  __syncthreads();
  int n = blockIdx.x*256 + tid;
  if (n >= NODES) return;
  float xv[5];
  #pragma unroll
  for (int k = 0; k < 5; k++) xv[k] = x[n*5 + k];
  float a[64];
  #pragma unroll
  for (int c = 0; c < 64; c++){
    float t = wb[c];
    #pragma unroll
    for (int k = 0; k < 5; k++) t += xv[k]*we[k*64 + c];
    a[c] = t;
  }
  float mean = 0.f;
  #pragma unroll
  for (int c = 0; c < 64; c++) mean += a[c];
  mean *= (1.f/64.f);
  float var = 0.f;
  #pragma unroll
  for (int c = 0; c < 64; c++){ float d = a[c]-mean; var += d*d; }
  var *= (1.f/64.f);
  float rstd = rsqrtf(var + 1e-5f);
  size_t rb = (size_t)n*64;
  #pragma unroll
  for (int c = 0; c < 64; c += 4){
    *(float4*)&h[rb + c] = make_float4(a[c], a[c+1], a[c+2], a[c+3]);
    float4 zv;
    zv.x = fmaxf((a[c  ]-mean)*rstd*sg[c  ]+sb[c  ], 0.f);
    zv.y = fmaxf((a[c+1]-mean)*rstd*sg[c+1]+sb[c+1], 0.f);
    zv.z = fmaxf((a[c+2]-mean)*rstd*sg[c+2]+sb[c+2], 0.f);
    zv.w = fmaxf((a[c+3]-mean)*rstd*sg[c+3]+sb[c+3], 0.f);
    *(float4*)&z[rb + c] = zv;
  }
}

// ---------------- GENConv softmax aggregation: u = z + agg ----------------
__global__ __launch_bounds__(256) void k_agg(const float* __restrict__ z, float* __restrict__ u,
    const int* __restrict__ rowptr, const int* __restrict__ esrc,
    const float* __restrict__ tparam, int li){
  int lane = threadIdx.x & 63;
  int n = blockIdx.x*4 + (threadIdx.x >> 6);
  if (n >= NODES) return;
  float tp = tparam[li];
  int beg = rowptr[n], end = rowptr[n+1];
  float den = 0.f, num = 0.f;
  for (int e = beg; e < end; ++e){
    int s = esrc[e];
    float msg = z[(size_t)s*64 + lane] + 1e-7f;
    float ex = expf(msg*tp);
    den += ex; num += msg*ex;
  }
  float agg = num / fmaxf(den, 1e-16f);
  u[(size_t)n*64 + lane] = z[(size_t)n*64 + lane] + agg;
}

// ---------------- node MLP: h += Lin2(relu(LN(Lin1(u)))); z_next or pool ----------------
__global__ __launch_bounds__(256, 1) void k_mlp(
    const float* __restrict__ u, float* __restrict__ h, float* __restrict__ znext,
    float* __restrict__ pooled, const int* __restrict__ batch,
    const float* __restrict__ W1, const float* __restrict__ B1,
    const float* __restrict__ G1, const float* __restrict__ Q1,
    const float* __restrict__ W2, const float* __restrict__ B2,
    const float* __restrict__ GN, const float* __restrict__ BN,
    int last){
  __shared__ __align__(16) float w1[64*128];
  __shared__ __align__(16) float w2[128*64];
  __shared__ float su[256*65];
  __shared__ float cb1[128], cg1[128], cq1[128];
  __shared__ float cb2[64], cgn[64], cbn[64];
  int tid = threadIdx.x;
  for (int i = tid; i < 8192; i += 256) w1[i] = W1[i];
  for (int i = tid; i < 8192; i += 256) w2[i] = W2[i];
  if (tid < 128){ cb1[tid] = B1[tid]; cg1[tid] = G1[tid]; cq1[tid] = Q1[tid]; }
  if (tid < 64){
    cb2[tid] = B2[tid];
    cgn[tid] = last ? 0.f : GN[tid];
    cbn[tid] = last ? 0.f : BN[tid];
  }
  int base = blockIdx.x*256;
  int nval = NODES - base; if (nval > 256) nval = 256;
  for (int i = tid; i < nval*64; i += 256)
    su[(i >> 6)*65 + (i & 63)] = u[(size_t)base*64 + i];
  __syncthreads();
  int n = base + tid;
  bool act = (tid < nval);
  float hd[128];
  #pragma unroll
  for (int j = 0; j < 128; j++) hd[j] = cb1[j];
  if (act){
    #pragma unroll 1
    for (int k = 0; k < 64; k++){
      float uk = su[tid*65 + k];
      const float4* wr = (const float4*)&w1[k*128];
      #pragma unroll
      for (int j = 0; j < 128; j += 4){
        float4 w = wr[j >> 2];
        hd[j] += uk*w.x; hd[j+1] += uk*w.y; hd[j+2] += uk*w.z; hd[j+3] += uk*w.w;
      }
    }
  }
  float mean = 0.f;
  #pragma unroll
  for (int j = 0; j < 128; j++) mean += hd[j];
  mean *= (1.f/128.f);
  float var = 0.f;
  #pragma unroll
  for (int j = 0; j < 128; j++){ float d = hd[j]-mean; var += d*d; }
  var *= (1.f/128.f);
  float rstd = rsqrtf(var + 1e-5f);
  __syncthreads();          // done reading u tile
  if (act){
    #pragma unroll
    for (int j = 0; j < 64; j++)
      su[tid*65 + j] = fmaxf((hd[j]-mean)*rstd*cg1[j] + cq1[j], 0.f);
  }
  __syncthreads();
  float out[64];
  #pragma unroll
  for (int c = 0; c < 64; c++) out[c] = cb2[c];
  if (act){
    #pragma unroll 1
    for (int j = 0; j < 64; j++){
      float aj = su[tid*65 + j];
      const float4* wr = (const float4*)&w2[j*64];
      #pragma unroll
      for (int c = 0; c < 64; c += 4){
        float4 w = wr[c >> 2];
        out[c] += aj*w.x; out[c+1] += aj*w.y; out[c+2] += aj*w.z; out[c+3] += aj*w.w;
      }
    }
  }
  __syncthreads();
  if (act){
    #pragma unroll
    for (int j = 64; j < 128; j++)
      su[tid*65 + (j-64)] = fmaxf((hd[j]-mean)*rstd*cg1[j] + cq1[j], 0.f);
  }
  __syncthreads();
  if (act){
    #pragma unroll 1
    for (int j = 0; j < 64; j++){
      float aj = su[tid*65 + j];
      const float4* wr = (const float4*)&w2[(j+64)*64];
      #pragma unroll
      for (int c = 0; c < 64; c += 4){
        float4 w = wr[c >> 2];
        out[c] += aj*w.x; out[c+1] += aj*w.y; out[c+2] += aj*w.z; out[c+3] += aj*w.w;
      }
    }
    size_t rb = (size_t)n*64;
    #pragma unroll
    for (int c = 0; c < 64; c += 4){
      float4 hv = *(const float4*)&h[rb + c];
      out[c] += hv.x; out[c+1] += hv.y; out[c+2] += hv.z; out[c+3] += hv.w;
    }
    if (!last){
      #pragma unroll
      for (int c = 0; c < 64; c += 4)
        *(float4*)&h[rb + c] = make_float4(out[c], out[c+1], out[c+2], out[c+3]);
      float m2 = 0.f;
      #pragma unroll
      for (int c = 0; c < 64; c++) m2 += out[c];
      m2 *= (1.f/64.f);
      float v2 = 0.f;
      #pragma unroll
      for (int c = 0; c < 64; c++){ float d = out[c]-m2; v2 += d*d; }
      v2 *= (1.f/64.f);
      float rs2 = rsqrtf(v2 + 1e-5f);
      #pragma unroll
      for (int c = 0; c < 64; c += 4){
        float4 zv;
        zv.x = fmaxf((out[c  ]-m2)*rs2*cgn[c  ]+cbn[c  ], 0.f);
        zv.y = fmaxf((out[c+1]-m2)*rs2*cgn[c+1]+cbn[c+1], 0.f);
        zv.z = fmaxf((out[c+2]-m2)*rs2*cgn[c+2]+cbn[c+2], 0.f);
        zv.w = fmaxf((out[c+3]-m2)*rs2*cgn[c+3]+cbn[c+3], 0.f);
        *(float4*)&znext[rb + c] = zv;
      }
    } else {
      int g = batch[n];
      #pragma unroll
      for (int c = 0; c < 64; c++) atomicAdd(&pooled[g*64 + c], out[c]);
    }
  }
}

// ---------------- pooled + var MLP -> t ; qkv for layer 0 ----------------
__global__ __launch_bounds__(128) void k_pool2(
    const float* __restrict__ pooled, const float* __restrict__ var_data,
    const float* __restrict__ v1W, const float* __restrict__ v1b,
    const float* __restrict__ v2W, const float* __restrict__ v2b,
    const float* __restrict__ v3W, const float* __restrict__ v3b,
    float* __restrict__ t, float* __restrict__ qkvout,
    const float* __restrict__ qW, const float* __restrict__ qb){
  __shared__ float vin[19], l1[16], l2[32], tr[128];
  int c = threadIdx.x, s = blockIdx.x;
  if (c < 19) vin[c] = var_data[s*19 + c];
  __syncthreads();
  if (c < 16){
    float a = v1b[c];
    for (int k = 0; k < 19; k++) a += vin[k]*v1W[k*16 + c];
    l1[c] = fmaxf(a, 0.f);
  }
  __syncthreads();
  if (c < 32){
    float a = v2b[c];
    for (int k = 0; k < 16; k++) a += l1[k]*v2W[k*32 + c];
    l2[c] = fmaxf(a, 0.f);
  }
  __syncthreads();
  float tv;
  if (c < 64) tv = pooled[s*64 + c];
  else {
    float a = v3b[c-64];
    for (int k = 0; k < 32; k++) a += l2[k]*v3W[k*64 + (c-64)];
    tv = a;
  }
  tr[c] = tv; t[s*128 + c] = tv;
  __syncthreads();
  #pragma unroll 1
  for (int r = 0; r < 3; r++){
    int col = r*128 + c;
    float a = qb[col];
    #pragma unroll 4
    for (int k = 0; k < 128; k++) a += tr[k]*qW[k*384 + col];
    qkvout[s*384 + col] = a;
  }
}

// ---------------- attention (8 heads, S=256, dh=16) ----------------
__global__ __launch_bounds__(256) void k_att(const float* __restrict__ qkv, float* __restrict__ oatt){
  __shared__ float kb[256*16];
  __shared__ float vb[256*16];
  int tid = threadIdx.x;
  int head = blockIdx.x >> 3;
  int tile = blockIdx.x & 7;
  int hb = head*16;
  for (int i = tid; i < 4096; i += 256){
    int s = i >> 4, d = i & 15;
    kb[i] = qkv[s*384 + 128 + hb + d];
    vb[i] = qkv[s*384 + 256 + hb + d];
  }
  __syncthreads();
  int row = tile*32 + (tid >> 3);
  int sub = tid & 7;
  float q[16];
  #pragma unroll
  for (int d = 0; d < 16; d++) q[d] = qkv[row*384 + hb + d];
  float sc[32];
  int k0 = sub*32;
  #pragma unroll
  for (int kk = 0; kk < 32; kk++){
    const float* kr = &kb[(k0+kk)*16];
    float s = 0.f;
    #pragma unroll
    for (int d = 0; d < 16; d++) s += q[d]*kr[d];
    sc[kk] = s*0.25f;
  }
  float m = -1e30f;
  #pragma unroll
  for (int kk = 0; kk < 32; kk++) m = fmaxf(m, sc[kk]);
  m = fmaxf(m, __shfl_xor(m, 1)); m = fmaxf(m, __shfl_xor(m, 2)); m = fmaxf(m, __shfl_xor(m, 4));
  float sum = 0.f;
  #pragma unroll
  for (int kk = 0; kk < 32; kk++){ sc[kk] = expf(sc[kk]-m); sum += sc[kk]; }
  sum += __shfl_xor(sum, 1); sum += __shfl_xor(sum, 2); sum += __shfl_xor(sum, 4);
  float o[16];
  #pragma unroll
  for (int d = 0; d < 16; d++) o[d] = 0.f;
  #pragma unroll
  for (int kk = 0; kk < 32; kk++){
    const float* vr = &vb[(k0+kk)*16];
    float p = sc[kk];
    #pragma unroll
    for (int d = 0; d < 16; d++) o[d] += p*vr[d];
  }
  float inv = 1.f/sum;
  #pragma unroll
  for (int d = 0; d < 16; d++){
    float tv = o[d];
    tv += __shfl_xor(tv, 1); tv += __shfl_xor(tv, 2); tv += __shfl_xor(tv, 4);
    if (sub == 0) oatt[row*128 + hb + d] = tv*inv;
  }
}

// ---------------- encoder row-local: oproj+LN1+FF+LN2 (+ next qkv / head) ----------------
__global__ __launch_bounds__(128) void k_row(
    const float* __restrict__ oatt, float* __restrict__ t, float* __restrict__ qkvout,
    const float* __restrict__ outW, const float* __restrict__ outb,
    const float* __restrict__ l1g, const float* __restrict__ l1b,
    const float* __restrict__ f1W, const float* __restrict__ f1b,
    const float* __restrict__ f2W, const float* __restrict__ f2b,
    const float* __restrict__ l2g, const float* __restrict__ l2b,
    const float* __restrict__ qW, const float* __restrict__ qb,
    const float* __restrict__ hW, const float* __restrict__ hb2,
    float* __restrict__ dout, int last){
  __shared__ float so[128], st[128], s1[128], sf[128];
  __shared__ float red[2];
  int c = threadIdx.x, s = blockIdx.x;
  so[c] = oatt[s*128 + c];
  st[c] = t[s*128 + c];
  __syncthreads();
  float acc = outb[c];
  #pragma unroll 4
  for (int k = 0; k < 128; k++) acc += so[k]*outW[k*128 + c];
  acc += st[c];
  float mean = blockSum128(acc, red)*(1.f/128.f);
  float d0 = acc - mean;
  float var = blockSum128(d0*d0, red)*(1.f/128.f);
  float t1 = d0*rsqrtf(var + 1e-5f)*l1g[c] + l1b[c];
  s1[c] = t1;
  __syncthreads();
  float f = f1b[c];
  #pragma unroll 4
  for (int k = 0; k < 128; k++) f += s1[k]*f1W[k*128 + c];
  f = 0.5f*f*(1.f + erff(f*0.70710678118654752f));
  sf[c] = f;
  __syncthreads();
  float g = f2b[c];
  #pragma unroll 4
  for (int k = 0; k < 128; k++) g += sf[k]*f2W[k*128 + c];
  g += t1;
  float mean2 = blockSum128(g, red)*(1.f/128.f);
  float d2 = g - mean2;
  float var2 = blockSum128(d2*d2, red)*(1.f/128.f);
  float t2 = d2*rsqrtf(var2 + 1e-5f)*l2g[c] + l2b[c];
  t[s*128 + c] = t2;
  __syncthreads();   // ensure s1 consumers done
  s1[c] = t2;
  __syncthreads();
  if (!last){
    #pragma unroll 1
    for (int r = 0; r < 3; r++){
      int col = r*128 + c;
      float a = qb[col];
      #pragma unroll 4
      for (int k = 0; k < 128; k++) a += s1[k]*qW[k*384 + col];
      qkvout[s*384 + col] = a;
    }
  } else {
    if (c < 2){
      float a = hb2[c];
      for (int k = 0; k < 128; k++) a += s1[k]*hW[k*2 + c];
      dout[s*2 + c] = a;
    }
  }
}

// ---------------- host ----------------
extern "C" void kernel_launch(void* const* d_in, const int* in_sizes, int n_in,
                              void* d_out, int out_size, void* d_ws, size_t ws_size,
                              hipStream_t stream){
  const float* x       = (const float*)d_in[0];
  const int*   ei      = (const int*)  d_in[1];
  const int*   batch   = (const int*)  d_in[2];
  const float* var_d   = (const float*)d_in[3];
  const float* encW    = (const float*)d_in[4];
  const float* encb    = (const float*)d_in[5];
  const float* ln_g    = (const float*)d_in[6];
  const float* ln_b    = (const float*)d_in[7];
  const float* tparam  = (const float*)d_in[8];
  const float* m1W     = (const float*)d_in[9];
  const float* m1b     = (const float*)d_in[10];
  const float* mng     = (const float*)d_in[11];
  const float* mnb     = (const float*)d_in[12];
  const float* m2W     = (const float*)d_in[13];
  const float* m2b     = (const float*)d_in[14];
  const float* v1W     = (const float*)d_in[15];
  const float* v1b     = (const float*)d_in[16];
  const float* v2W     = (const float*)d_in[17];
  const float* v2b     = (const float*)d_in[18];
  const float* v3W     = (const float*)d_in[19];
  const float* v3b     = (const float*)d_in[20];
  const float* qkvW    = (const float*)d_in[21];
  const float* qkvB    = (const float*)d_in[22];
  const float* outW    = (const float*)d_in[23];
  const float* outb    = (const float*)d_in[24];
  const float* l1g     = (const float*)d_in[25];
  const float* l1b     = (const float*)d_in[26];
  const float* f1W     = (const float*)d_in[27];
  const float* f1b     = (const float*)d_in[28];
  const float* f2W     = (const float*)d_in[29];
  const float* f2b     = (const float*)d_in[30];
  const float* l2g     = (const float*)d_in[31];
  const float* l2b     = (const float*)d_in[32];
  const float* headW   = (const float*)d_in[33];
  const float* headB   = (const float*)d_in[34];
  float* dout = (float*)d_out;

  char* wsb = (char*)d_ws;
  size_t off = 0;
  auto nxt = [&](size_t bytes)->void*{
    void* p = wsb + off;
    off += (bytes + 255) & ~(size_t)255;
    return p;
  };
  float* h      = (float*)nxt((size_t)NODES*64*4);
  float* z      = (float*)nxt((size_t)NODES*64*4);
  float* u      = (float*)nxt((size_t)NODES*64*4);
  int*   rowptr = (int*)  nxt((size_t)(NODES+1)*4);
  int*   cursor = (int*)  nxt((size_t)NODES*4);
  int*   counts = (int*)  nxt((size_t)NODES*4);
  int*   bsums  = (int*)  nxt(64*4);
  int*   boffs  = (int*)  nxt(64*4);
  int*   esrc   = (int*)  nxt((size_t)EDGES*4);
  float* pooled = (float*)nxt((size_t)NG*64*4);
  float* tbuf   = (float*)nxt((size_t)NG*128*4);
  float* qkvb   = (float*)nxt((size_t)NG*384*4);
  float* oatt   = (float*)nxt((size_t)NG*128*4);

  const int* srcp = ei;
  const int* dstp = ei + EDGES;

  k_zero_i <<<391, 256, 0, stream>>>(counts, NODES);
  k_hist   <<<4688, 256, 0, stream>>>(dstp, counts);
  k_scan1  <<<49, 256, 0, stream>>>(counts, rowptr, bsums);
  k_scan2  <<<1, 64, 0, stream>>>(bsums, boffs, 49);
  k_scan3  <<<391, 256, 0, stream>>>(rowptr, cursor, boffs);
  k_scatter<<<4688, 256, 0, stream>>>(srcp, dstp, cursor, esrc);
  k_zero_f <<<64, 256, 0, stream>>>(pooled, NG*64);
  k_enc    <<<391, 256, 0, stream>>>(x, encW, encb, ln_g, ln_b, h, z);

  for (int i = 0; i < 6; i++){
    int last = (i == 5);
    k_agg<<<25000, 256, 0, stream>>>(z, u, rowptr, esrc, tparam, i);
    k_mlp<<<391, 256, 0, stream>>>(u, h, z, pooled, batch,
        m1W + i*8192, m1b + i*128, mng + i*128, mnb + i*128,
        m2W + i*8192, m2b + i*64,
        ln_g + (last ? 0 : (i+1)*64), ln_b + (last ? 0 : (i+1)*64), last);
  }

  k_pool2<<<NG, 128, 0, stream>>>(pooled, var_d, v1W, v1b, v2W, v2b, v3W, v3b,
                                  tbuf, qkvb, qkvW, qkvB);

  for (int i = 0; i < 6; i++){
    int last = (i == 5);
    k_att<<<64, 256, 0, stream>>>(qkvb, oatt);
    k_row<<<NG, 128, 0, stream>>>(oatt, tbuf, qkvb,
        outW + i*16384, outb + i*128, l1g + i*128, l1b + i*128,
        f1W + i*16384, f1b + i*128, f2W + i*16384, f2b + i*128,
        l2g + i*128, l2b + i*128,
        qkvW + (size_t)(last ? 0 : (i+1))*49152, qkvB + (last ? 0 : (i+1))*384,
        headW, headB, dout, last);
  }
}

// Round 3
// 2883.585 us; speedup vs baseline: 1.0386x; 1.0386x over previous
//
#include <hip/hip_runtime.h>
#include <math.h>

#define NODES 100000
#define EDGES 1200000
#define NG 256

// ---------------- utility ----------------
__device__ __forceinline__ float wsum64(float v){
  v += __shfl_xor(v, 32); v += __shfl_xor(v, 16); v += __shfl_xor(v, 8);
  v += __shfl_xor(v, 4);  v += __shfl_xor(v, 2);  v += __shfl_xor(v, 1);
  return v;
}

__device__ __forceinline__ float blockSum128(float v, float* red){
  v = wsum64(v);
  if ((threadIdx.x & 63) == 0) red[threadIdx.x >> 6] = v;
  __syncthreads();
  float r = red[0] + red[1];
  __syncthreads();
  return r;
}

__global__ void k_zero_i(int* p, int n){ int i = blockIdx.x*256 + threadIdx.x; if (i < n) p[i] = 0; }
__global__ void k_zero_f(float* p, int n){ int i = blockIdx.x*256 + threadIdx.x; if (i < n) p[i] = 0.f; }

// ---------------- CSR build ----------------
__global__ void k_hist(const int* __restrict__ dst, int* __restrict__ counts){
  int e = blockIdx.x*256 + threadIdx.x;
  if (e < EDGES) atomicAdd(&counts[dst[e]], 1);
}

__global__ void k_scan1(const int* __restrict__ counts, int* __restrict__ rowptr, int* __restrict__ bsums){
  __shared__ int sd[256];
  int tid = threadIdx.x;
  int base = blockIdx.x*2048 + tid*8;
  int v[8]; int s = 0;
  #pragma unroll
  for (int i = 0; i < 8; i++){
    int idx = base + i;
    int c = (idx < NODES) ? counts[idx] : 0;
    v[i] = s; s += c;
  }
  sd[tid] = s;
  __syncthreads();
  for (int off = 1; off < 256; off <<= 1){
    int t = 0;
    if (tid >= off) t = sd[tid - off];
    __syncthreads();
    if (tid >= off) sd[tid] += t;
    __syncthreads();
  }
  int excl = (tid > 0) ? sd[tid-1] : 0;
  #pragma unroll
  for (int i = 0; i < 8; i++){
    int idx = base + i;
    if (idx < NODES) rowptr[idx] = v[i] + excl;
  }
  if (tid == 255) bsums[blockIdx.x] = sd[255];
}

__global__ void k_scan2(const int* __restrict__ bsums, int* __restrict__ boffs, int nb){
  if (threadIdx.x == 0 && blockIdx.x == 0){
    int run = 0;
    for (int b = 0; b < nb; b++){ boffs[b] = run; run += bsums[b]; }
  }
}

__global__ void k_scan3(int* __restrict__ rowptr, int* __restrict__ cursor, const int* __restrict__ boffs){
  int i = blockIdx.x*256 + threadIdx.x;
  if (i < NODES){
    int r = rowptr[i] + boffs[i >> 11];
    rowptr[i] = r; cursor[i] = r;
  }
  if (i == 0) rowptr[NODES] = EDGES;
}

__global__ void k_scatter(const int* __restrict__ src, const int* __restrict__ dst,
                          int* __restrict__ cursor, int* __restrict__ esrc){
  int e = blockIdx.x*256 + threadIdx.x;
  if (e < EDGES){
    int d = dst[e];
    int p = atomicAdd(&cursor[d], 1);
    esrc[p] = src[e];
  }
}

// ---------------- encoder: h = x@W+b ; z = relu(LN(h)) ----------------
__global__ __launch_bounds__(256) void k_enc(const float* __restrict__ x,
    const float* __restrict__ encW, const float* __restrict__ encb,
    const float* __restrict__ lg, const float* __restrict__ lb,
    float* __restrict__ h, float* __restrict__ z){
  __shared__ float we[320], wb[64], sg[64], sb[64];
  int tid = threadIdx.x;
  for (int i = tid; i < 320; i += 256) we[i] = encW[i];
  if (tid < 64){ wb[tid] = encb[tid]; sg[tid] = lg[tid]; sb[tid] = lb[tid]; }
  __syncthreads();
  int n = blockIdx.x*256 + tid;
  if (n >= NODES) return;
  float xv[5];
  #pragma unroll
  for (int k = 0; k < 5; k++) xv[k] = x[n*5 + k];
  float a[64];
  #pragma unroll
  for (int c = 0; c < 64; c++){
    float t = wb[c];
    #pragma unroll
    for (int k = 0; k < 5; k++) t += xv[k]*we[k*64 + c];
    a[c] = t;
  }
  float mean = 0.f;
  #pragma unroll
  for (int c = 0; c < 64; c++) mean += a[c];
  mean *= (1.f/64.f);
  float var = 0.f;
  #pragma unroll
  for (int c = 0; c < 64; c++){ float d = a[c]-mean; var += d*d; }
  var *= (1.f/64.f);
  float rstd = rsqrtf(var + 1e-5f);
  size_t rb = (size_t)n*64;
  #pragma unroll
  for (int c = 0; c < 64; c += 4){
    *(float4*)&h[rb + c] = make_float4(a[c], a[c+1], a[c+2], a[c+3]);
    float4 zv;
    zv.x = fmaxf((a[c  ]-mean)*rstd*sg[c  ]+sb[c  ], 0.f);
    zv.y = fmaxf((a[c+1]-mean)*rstd*sg[c+1]+sb[c+1], 0.f);
    zv.z = fmaxf((a[c+2]-mean)*rstd*sg[c+2]+sb[c+2], 0.f);
    zv.w = fmaxf((a[c+3]-mean)*rstd*sg[c+3]+sb[c+3], 0.f);
    *(float4*)&z[rb + c] = zv;
  }
}

// ---------------- GENConv softmax aggregation: u = z + agg ----------------
__global__ __launch_bounds__(256) void k_agg(const float* __restrict__ z, float* __restrict__ u,
    const int* __restrict__ rowptr, const int* __restrict__ esrc,
    const float* __restrict__ tparam, int li){
  int lane = threadIdx.x & 63;
  int n = blockIdx.x*4 + (threadIdx.x >> 6);
  if (n >= NODES) return;
  float tp = tparam[li];
  int beg = rowptr[n], end = rowptr[n+1];
  float den = 0.f, num = 0.f;
  for (int e = beg; e < end; ++e){
    int s = esrc[e];
    float msg = z[(size_t)s*64 + lane] + 1e-7f;
    float ex = __expf(msg*tp);
    den += ex; num += msg*ex;
  }
  float agg = num / fmaxf(den, 1e-16f);
  u[(size_t)n*64 + lane] = z[(size_t)n*64 + lane] + agg;
}

// ---------------- MLP part A: act = relu(LN(u @ W1 + b1)) ----------------
// 4 threads per node; thread q computes hd[q*32 .. q*32+31].
__global__ __launch_bounds__(256) void k_mlpa(
    const float* __restrict__ u, float* __restrict__ act,
    const float* __restrict__ W1, const float* __restrict__ B1,
    const float* __restrict__ G1, const float* __restrict__ Q1){
  __shared__ __align__(16) float w1s[64*128];   // 32 KB
  __shared__ float su[64*65];                   // 16.6 KB u tile (64 nodes)
  __shared__ float cb1[128], cg1[128], cq1[128];
  int tid = threadIdx.x;
  for (int i = tid; i < 8192; i += 256) w1s[i] = W1[i];
  if (tid < 128){ cb1[tid] = B1[tid]; cg1[tid] = G1[tid]; cq1[tid] = Q1[tid]; }
  int base = blockIdx.x*64;
  int nval = NODES - base; if (nval > 64) nval = 64;
  if (nval < 0) nval = 0;
  for (int i = tid; i < nval*64; i += 256)
    su[(i >> 6)*65 + (i & 63)] = u[(size_t)base*64 + i];
  __syncthreads();
  int nl = tid >> 2;          // local node 0..63
  int q  = tid & 3;           // quarter
  int n  = base + nl;
  if (nl >= nval) return;
  int jb = q*32;
  float hd[32];
  #pragma unroll
  for (int j = 0; j < 32; j++) hd[j] = cb1[jb + j];
  #pragma unroll 2
  for (int k = 0; k < 64; k++){
    float uk = su[nl*65 + k];
    const float4* wr = (const float4*)&w1s[k*128 + jb];
    #pragma unroll
    for (int j4 = 0; j4 < 8; j4++){
      float4 w = wr[j4];
      hd[j4*4  ] += uk*w.x; hd[j4*4+1] += uk*w.y;
      hd[j4*4+2] += uk*w.z; hd[j4*4+3] += uk*w.w;
    }
  }
  // LN over 128 (quad reduce)
  float s = 0.f;
  #pragma unroll
  for (int j = 0; j < 32; j++) s += hd[j];
  s += __shfl_xor(s, 1); s += __shfl_xor(s, 2);
  float mean = s*(1.f/128.f);
  float vs = 0.f;
  #pragma unroll
  for (int j = 0; j < 32; j++){ float d = hd[j]-mean; vs += d*d; }
  vs += __shfl_xor(vs, 1); vs += __shfl_xor(vs, 2);
  float rstd = rsqrtf(vs*(1.f/128.f) + 1e-5f);
  float* arow = act + (size_t)n*128 + jb;
  #pragma unroll
  for (int j4 = 0; j4 < 8; j4++){
    float4 av;
    av.x = fmaxf((hd[j4*4  ]-mean)*rstd*cg1[jb+j4*4  ] + cq1[jb+j4*4  ], 0.f);
    av.y = fmaxf((hd[j4*4+1]-mean)*rstd*cg1[jb+j4*4+1] + cq1[jb+j4*4+1], 0.f);
    av.z = fmaxf((hd[j4*4+2]-mean)*rstd*cg1[jb+j4*4+2] + cq1[jb+j4*4+2], 0.f);
    av.w = fmaxf((hd[j4*4+3]-mean)*rstd*cg1[jb+j4*4+3] + cq1[jb+j4*4+3], 0.f);
    *(float4*)&arow[j4*4] = av;
  }
}

// ---------------- MLP part B: h += act @ W2 + b2 ; znext or pool ----------------
// 4 threads per node; thread q computes out[q*16 .. q*16+15].
__global__ __launch_bounds__(256) void k_mlpb(
    const float* __restrict__ act, float* __restrict__ h, float* __restrict__ znext,
    float* __restrict__ pooled, const int* __restrict__ batch,
    const float* __restrict__ W2, const float* __restrict__ B2,
    const float* __restrict__ GN, const float* __restrict__ BN,
    int last){
  __shared__ __align__(16) float w2s[128*64];   // 32 KB
  __shared__ float cb2[64], cgn[64], cbn[64];
  int tid = threadIdx.x;
  for (int i = tid; i < 8192; i += 256) w2s[i] = W2[i];
  if (tid < 64){
    cb2[tid] = B2[tid];
    cgn[tid] = last ? 0.f : GN[tid];
    cbn[tid] = last ? 0.f : BN[tid];
  }
  __syncthreads();
  int gid = blockIdx.x*256 + tid;
  int n = gid >> 2;
  int q = gid & 3;
  if (n >= NODES) return;
  int cb = q*16;
  float out[16];
  #pragma unroll
  for (int c = 0; c < 16; c++) out[c] = cb2[cb + c];
  const float4* arow = (const float4*)(act + (size_t)n*128);
  #pragma unroll 2
  for (int m4 = 0; m4 < 32; m4++){
    float4 av = arow[m4];
    #pragma unroll
    for (int mm = 0; mm < 4; mm++){
      float aj = (mm == 0) ? av.x : (mm == 1) ? av.y : (mm == 2) ? av.z : av.w;
      const float4* wr = (const float4*)&w2s[(m4*4 + mm)*64 + cb];
      #pragma unroll
      for (int c4 = 0; c4 < 4; c4++){
        float4 w = wr[c4];
        out[c4*4  ] += aj*w.x; out[c4*4+1] += aj*w.y;
        out[c4*4+2] += aj*w.z; out[c4*4+3] += aj*w.w;
      }
    }
  }
  size_t rb = (size_t)n*64 + cb;
  #pragma unroll
  for (int c4 = 0; c4 < 4; c4++){
    float4 hv = *(const float4*)&h[rb + c4*4];
    out[c4*4  ] += hv.x; out[c4*4+1] += hv.y;
    out[c4*4+2] += hv.z; out[c4*4+3] += hv.w;
  }
  if (!last){
    #pragma unroll
    for (int c4 = 0; c4 < 4; c4++)
      *(float4*)&h[rb + c4*4] = make_float4(out[c4*4], out[c4*4+1], out[c4*4+2], out[c4*4+3]);
    // next-layer z = relu(LN64(h_new))
    float s = 0.f;
    #pragma unroll
    for (int c = 0; c < 16; c++) s += out[c];
    s += __shfl_xor(s, 1); s += __shfl_xor(s, 2);
    float mean = s*(1.f/64.f);
    float vs = 0.f;
    #pragma unroll
    for (int c = 0; c < 16; c++){ float d = out[c]-mean; vs += d*d; }
    vs += __shfl_xor(vs, 1); vs += __shfl_xor(vs, 2);
    float rstd = rsqrtf(vs*(1.f/64.f) + 1e-5f);
    #pragma unroll
    for (int c4 = 0; c4 < 4; c4++){
      float4 zv;
      zv.x = fmaxf((out[c4*4  ]-mean)*rstd*cgn[cb+c4*4  ] + cbn[cb+c4*4  ], 0.f);
      zv.y = fmaxf((out[c4*4+1]-mean)*rstd*cgn[cb+c4*4+1] + cbn[cb+c4*4+1], 0.f);
      zv.z = fmaxf((out[c4*4+2]-mean)*rstd*cgn[cb+c4*4+2] + cbn[cb+c4*4+2], 0.f);
      zv.w = fmaxf((out[c4*4+3]-mean)*rstd*cgn[cb+c4*4+3] + cbn[cb+c4*4+3], 0.f);
      *(float4*)&znext[rb + c4*4] = zv;
    }
  } else {
    int g = batch[n];
    #pragma unroll
    for (int c = 0; c < 16; c++) atomicAdd(&pooled[g*64 + cb + c], out[c]);
  }
}

// ---------------- pooled + var MLP -> t ; qkv for layer 0 ----------------
__global__ __launch_bounds__(128) void k_pool2(
    const float* __restrict__ pooled, const float* __restrict__ var_data,
    const float* __restrict__ v1W, const float* __restrict__ v1b,
    const float* __restrict__ v2W, const float* __restrict__ v2b,
    const float* __restrict__ v3W, const float* __restrict__ v3b,
    float* __restrict__ t, float* __restrict__ qkvout,
    const float* __restrict__ qW, const float* __restrict__ qb){
  __shared__ float vin[19], l1[16], l2[32], tr[128];
  int c = threadIdx.x, s = blockIdx.x;
  if (c < 19) vin[c] = var_data[s*19 + c];
  __syncthreads();
  if (c < 16){
    float a = v1b[c];
    for (int k = 0; k < 19; k++) a += vin[k]*v1W[k*16 + c];
    l1[c] = fmaxf(a, 0.f);
  }
  __syncthreads();
  if (c < 32){
    float a = v2b[c];
    for (int k = 0; k < 16; k++) a += l1[k]*v2W[k*32 + c];
    l2[c] = fmaxf(a, 0.f);
  }
  __syncthreads();
  float tv;
  if (c < 64) tv = pooled[s*64 + c];
  else {
    float a = v3b[c-64];
    for (int k = 0; k < 32; k++) a += l2[k]*v3W[k*64 + (c-64)];
    tv = a;
  }
  tr[c] = tv; t[s*128 + c] = tv;
  __syncthreads();
  #pragma unroll 1
  for (int r = 0; r < 3; r++){
    int col = r*128 + c;
    float a = qb[col];
    #pragma unroll 4
    for (int k = 0; k < 128; k++) a += tr[k]*qW[k*384 + col];
    qkvout[s*384 + col] = a;
  }
}

// ---------------- attention (8 heads, S=256, dh=16) ----------------
__global__ __launch_bounds__(256) void k_att(const float* __restrict__ qkv, float* __restrict__ oatt){
  __shared__ float kb[256*16];
  __shared__ float vb[256*16];
  int tid = threadIdx.x;
  int head = blockIdx.x >> 3;
  int tile = blockIdx.x & 7;
  int hb = head*16;
  for (int i = tid; i < 4096; i += 256){
    int s = i >> 4, d = i & 15;
    kb[i] = qkv[s*384 + 128 + hb + d];
    vb[i] = qkv[s*384 + 256 + hb + d];
  }
  __syncthreads();
  int row = tile*32 + (tid >> 3);
  int sub = tid & 7;
  float q[16];
  #pragma unroll
  for (int d = 0; d < 16; d++) q[d] = qkv[row*384 + hb + d];
  float sc[32];
  int k0 = sub*32;
  #pragma unroll
  for (int kk = 0; kk < 32; kk++){
    const float* kr = &kb[(k0+kk)*16];
    float s = 0.f;
    #pragma unroll
    for (int d = 0; d < 16; d++) s += q[d]*kr[d];
    sc[kk] = s*0.25f;
  }
  float m = -1e30f;
  #pragma unroll
  for (int kk = 0; kk < 32; kk++) m = fmaxf(m, sc[kk]);
  m = fmaxf(m, __shfl_xor(m, 1)); m = fmaxf(m, __shfl_xor(m, 2)); m = fmaxf(m, __shfl_xor(m, 4));
  float sum = 0.f;
  #pragma unroll
  for (int kk = 0; kk < 32; kk++){ sc[kk] = __expf(sc[kk]-m); sum += sc[kk]; }
  sum += __shfl_xor(sum, 1); sum += __shfl_xor(sum, 2); sum += __shfl_xor(sum, 4);
  float o[16];
  #pragma unroll
  for (int d = 0; d < 16; d++) o[d] = 0.f;
  #pragma unroll
  for (int kk = 0; kk < 32; kk++){
    const float* vr = &vb[(k0+kk)*16];
    float p = sc[kk];
    #pragma unroll
    for (int d = 0; d < 16; d++) o[d] += p*vr[d];
  }
  float inv = 1.f/sum;
  #pragma unroll
  for (int d = 0; d < 16; d++){
    float tv = o[d];
    tv += __shfl_xor(tv, 1); tv += __shfl_xor(tv, 2); tv += __shfl_xor(tv, 4);
    if (sub == 0) oatt[row*128 + hb + d] = tv*inv;
  }
}

// ---------------- encoder row-local: oproj+LN1+FF+LN2 (+ next qkv / head) ----------------
__global__ __launch_bounds__(128) void k_row(
    const float* __restrict__ oatt, float* __restrict__ t, float* __restrict__ qkvout,
    const float* __restrict__ outW, const float* __restrict__ outb,
    const float* __restrict__ l1g, const float* __restrict__ l1b,
    const float* __restrict__ f1W, const float* __restrict__ f1b,
    const float* __restrict__ f2W, const float* __restrict__ f2b,
    const float* __restrict__ l2g, const float* __restrict__ l2b,
    const float* __restrict__ qW, const float* __restrict__ qb,
    const float* __restrict__ hW, const float* __restrict__ hb2,
    float* __restrict__ dout, int last){
  __shared__ float so[128], st[128], s1[128], sf[128];
  __shared__ float red[2];
  int c = threadIdx.x, s = blockIdx.x;
  so[c] = oatt[s*128 + c];
  st[c] = t[s*128 + c];
  __syncthreads();
  float acc = outb[c];
  #pragma unroll 4
  for (int k = 0; k < 128; k++) acc += so[k]*outW[k*128 + c];
  acc += st[c];
  float mean = blockSum128(acc, red)*(1.f/128.f);
  float d0 = acc - mean;
  float var = blockSum128(d0*d0, red)*(1.f/128.f);
  float t1 = d0*rsqrtf(var + 1e-5f)*l1g[c] + l1b[c];
  s1[c] = t1;
  __syncthreads();
  float f = f1b[c];
  #pragma unroll 4
  for (int k = 0; k < 128; k++) f += s1[k]*f1W[k*128 + c];
  f = 0.5f*f*(1.f + erff(f*0.70710678118654752f));
  sf[c] = f;
  __syncthreads();
  float g = f2b[c];
  #pragma unroll 4
  for (int k = 0; k < 128; k++) g += sf[k]*f2W[k*128 + c];
  g += t1;
  float mean2 = blockSum128(g, red)*(1.f/128.f);
  float d2 = g - mean2;
  float var2 = blockSum128(d2*d2, red)*(1.f/128.f);
  float t2 = d2*rsqrtf(var2 + 1e-5f)*l2g[c] + l2b[c];
  t[s*128 + c] = t2;
  __syncthreads();
  s1[c] = t2;
  __syncthreads();
  if (!last){
    #pragma unroll 1
    for (int r = 0; r < 3; r++){
      int col = r*128 + c;
      float a = qb[col];
      #pragma unroll 4
      for (int k = 0; k < 128; k++) a += s1[k]*qW[k*384 + col];
      qkvout[s*384 + col] = a;
    }
  } else {
    if (c < 2){
      float a = hb2[c];
      for (int k = 0; k < 128; k++) a += s1[k]*hW[k*2 + c];
      dout[s*2 + c] = a;
    }
  }
}

// ---------------- host ----------------
extern "C" void kernel_launch(void* const* d_in, const int* in_sizes, int n_in,
                              void* d_out, int out_size, void* d_ws, size_t ws_size,
                              hipStream_t stream){
  const float* x       = (const float*)d_in[0];
  const int*   ei      = (const int*)  d_in[1];
  const int*   batch   = (const int*)  d_in[2];
  const float* var_d   = (const float*)d_in[3];
  const float* encW    = (const float*)d_in[4];
  const float* encb    = (const float*)d_in[5];
  const float* ln_g    = (const float*)d_in[6];
  const float* ln_b    = (const float*)d_in[7];
  const float* tparam  = (const float*)d_in[8];
  const float* m1W     = (const float*)d_in[9];
  const float* m1b     = (const float*)d_in[10];
  const float* mng     = (const float*)d_in[11];
  const float* mnb     = (const float*)d_in[12];
  const float* m2W     = (const float*)d_in[13];
  const float* m2b     = (const float*)d_in[14];
  const float* v1W     = (const float*)d_in[15];
  const float* v1b     = (const float*)d_in[16];
  const float* v2W     = (const float*)d_in[17];
  const float* v2b     = (const float*)d_in[18];
  const float* v3W     = (const float*)d_in[19];
  const float* v3b     = (const float*)d_in[20];
  const float* qkvW    = (const float*)d_in[21];
  const float* qkvB    = (const float*)d_in[22];
  const float* outW    = (const float*)d_in[23];
  const float* outb    = (const float*)d_in[24];
  const float* l1g     = (const float*)d_in[25];
  const float* l1b     = (const float*)d_in[26];
  const float* f1W     = (const float*)d_in[27];
  const float* f1b     = (const float*)d_in[28];
  const float* f2W     = (const float*)d_in[29];
  const float* f2b     = (const float*)d_in[30];
  const float* l2g     = (const float*)d_in[31];
  const float* l2b     = (const float*)d_in[32];
  const float* headW   = (const float*)d_in[33];
  const float* headB   = (const float*)d_in[34];
  float* dout = (float*)d_out;

  char* wsb = (char*)d_ws;
  size_t off = 0;
  auto nxt = [&](size_t bytes)->void*{
    void* p = wsb + off;
    off += (bytes + 255) & ~(size_t)255;
    return p;
  };
  float* h      = (float*)nxt((size_t)NODES*64*4);
  float* z      = (float*)nxt((size_t)NODES*64*4);
  float* u      = (float*)nxt((size_t)NODES*64*4);
  int*   rowptr = (int*)  nxt((size_t)(NODES+1)*4);
  int*   cursor = (int*)  nxt((size_t)NODES*4);
  int*   counts = (int*)  nxt((size_t)NODES*4);
  int*   bsums  = (int*)  nxt(64*4);
  int*   boffs  = (int*)  nxt(64*4);
  int*   esrc   = (int*)  nxt((size_t)EDGES*4);
  float* pooled = (float*)nxt((size_t)NG*64*4);
  float* tbuf   = (float*)nxt((size_t)NG*128*4);
  float* qkvb   = (float*)nxt((size_t)NG*384*4);
  float* oatt   = (float*)nxt((size_t)NG*128*4);
  float* act    = (float*)nxt((size_t)NODES*128*4);

  const int* srcp = ei;
  const int* dstp = ei + EDGES;

  k_zero_i <<<391, 256, 0, stream>>>(counts, NODES);
  k_hist   <<<4688, 256, 0, stream>>>(dstp, counts);
  k_scan1  <<<49, 256, 0, stream>>>(counts, rowptr, bsums);
  k_scan2  <<<1, 64, 0, stream>>>(bsums, boffs, 49);
  k_scan3  <<<391, 256, 0, stream>>>(rowptr, cursor, boffs);
  k_scatter<<<4688, 256, 0, stream>>>(srcp, dstp, cursor, esrc);
  k_zero_f <<<64, 256, 0, stream>>>(pooled, NG*64);
  k_enc    <<<391, 256, 0, stream>>>(x, encW, encb, ln_g, ln_b, h, z);

  for (int i = 0; i < 6; i++){
    int last = (i == 5);
    k_agg <<<25000, 256, 0, stream>>>(z, u, rowptr, esrc, tparam, i);
    k_mlpa<<<1563, 256, 0, stream>>>(u, act,
        m1W + i*8192, m1b + i*128, mng + i*128, mnb + i*128);
    k_mlpb<<<1563, 256, 0, stream>>>(act, h, z, pooled, batch,
        m2W + i*8192, m2b + i*64,
        ln_g + (last ? 0 : (i+1)*64), ln_b + (last ? 0 : (i+1)*64), last);
  }

  k_pool2<<<NG, 128, 0, stream>>>(pooled, var_d, v1W, v1b, v2W, v2b, v3W, v3b,
                                  tbuf, qkvb, qkvW, qkvB);

  for (int i = 0; i < 6; i++){
    int last = (i == 5);
    k_att<<<64, 256, 0, stream>>>(qkvb, oatt);
    k_row<<<NG, 128, 0, stream>>>(oatt, tbuf, qkvb,
        outW + i*16384, outb + i*128, l1g + i*128, l1b + i*128,
        f1W + i*16384, f1b + i*128, f2W + i*16384, f2b + i*128,
        l2g + i*128, l2b + i*128,
        qkvW + (size_t)(last ? 0 : (i+1))*49152, qkvB + (last ? 0 : (i+1))*384,
        headW, headB, dout, last);
  }
}

// Round 4
// 2555.019 us; speedup vs baseline: 1.1722x; 1.1286x over previous
//
#include <hip/hip_runtime.h>
#include <hip/hip_bf16.h>
#include <math.h>

#define NODES 100000
#define EDGES 1200000
#define NG 256

typedef unsigned short u16;
typedef unsigned int   u32;

// bf16 helpers: RNE pack, cheap unpack (values are finite; no NaN handling needed)
__device__ __forceinline__ u16 f2bf(float f){
  u32 u = __float_as_uint(f);
  u32 r = (u + 0x7FFFu + ((u >> 16) & 1u)) >> 16;
  return (u16)r;
}
__device__ __forceinline__ float bf2f(u16 b){ return __uint_as_float(((u32)b) << 16); }

// ---------------- utility ----------------
__device__ __forceinline__ float wsum64(float v){
  v += __shfl_xor(v, 32); v += __shfl_xor(v, 16); v += __shfl_xor(v, 8);
  v += __shfl_xor(v, 4);  v += __shfl_xor(v, 2);  v += __shfl_xor(v, 1);
  return v;
}

__device__ __forceinline__ float blockSum128(float v, float* red){
  v = wsum64(v);
  if ((threadIdx.x & 63) == 0) red[threadIdx.x >> 6] = v;
  __syncthreads();
  float r = red[0] + red[1];
  __syncthreads();
  return r;
}

__global__ void k_zero_i(int* p, int n){ int i = blockIdx.x*256 + threadIdx.x; if (i < n) p[i] = 0; }
__global__ void k_zero_f(float* p, int n){ int i = blockIdx.x*256 + threadIdx.x; if (i < n) p[i] = 0.f; }

// ---------------- CSR build ----------------
__global__ void k_hist(const int* __restrict__ dst, int* __restrict__ counts){
  int e = blockIdx.x*256 + threadIdx.x;
  if (e < EDGES) atomicAdd(&counts[dst[e]], 1);
}

__global__ void k_scan1(const int* __restrict__ counts, int* __restrict__ rowptr, int* __restrict__ bsums){
  __shared__ int sd[256];
  int tid = threadIdx.x;
  int base = blockIdx.x*2048 + tid*8;
  int v[8]; int s = 0;
  #pragma unroll
  for (int i = 0; i < 8; i++){
    int idx = base + i;
    int c = (idx < NODES) ? counts[idx] : 0;
    v[i] = s; s += c;
  }
  sd[tid] = s;
  __syncthreads();
  for (int off = 1; off < 256; off <<= 1){
    int t = 0;
    if (tid >= off) t = sd[tid - off];
    __syncthreads();
    if (tid >= off) sd[tid] += t;
    __syncthreads();
  }
  int excl = (tid > 0) ? sd[tid-1] : 0;
  #pragma unroll
  for (int i = 0; i < 8; i++){
    int idx = base + i;
    if (idx < NODES) rowptr[idx] = v[i] + excl;
  }
  if (tid == 255) bsums[blockIdx.x] = sd[255];
}

__global__ void k_scan2(const int* __restrict__ bsums, int* __restrict__ boffs, int nb){
  if (threadIdx.x == 0 && blockIdx.x == 0){
    int run = 0;
    for (int b = 0; b < nb; b++){ boffs[b] = run; run += bsums[b]; }
  }
}

__global__ void k_scan3(int* __restrict__ rowptr, int* __restrict__ cursor, const int* __restrict__ boffs){
  int i = blockIdx.x*256 + threadIdx.x;
  if (i < NODES){
    int r = rowptr[i] + boffs[i >> 11];
    rowptr[i] = r; cursor[i] = r;
  }
  if (i == 0) rowptr[NODES] = EDGES;
}

__global__ void k_scatter(const int* __restrict__ src, const int* __restrict__ dst,
                          int* __restrict__ cursor, int* __restrict__ esrc){
  int e = blockIdx.x*256 + threadIdx.x;
  if (e < EDGES){
    int d = dst[e];
    int p = atomicAdd(&cursor[d], 1);
    esrc[p] = src[e];
  }
}

// ---------------- encoder: h = x@W+b ; z = relu(LN(h)) [z -> bf16] ----------------
__global__ __launch_bounds__(256) void k_enc(const float* __restrict__ x,
    const float* __restrict__ encW, const float* __restrict__ encb,
    const float* __restrict__ lg, const float* __restrict__ lb,
    float* __restrict__ h, u16* __restrict__ z){
  __shared__ float we[320], wb[64], sg[64], sb[64];
  int tid = threadIdx.x;
  for (int i = tid; i < 320; i += 256) we[i] = encW[i];
  if (tid < 64){ wb[tid] = encb[tid]; sg[tid] = lg[tid]; sb[tid] = lb[tid]; }
  __syncthreads();
  int n = blockIdx.x*256 + tid;
  if (n >= NODES) return;
  float xv[5];
  #pragma unroll
  for (int k = 0; k < 5; k++) xv[k] = x[n*5 + k];
  float a[64];
  #pragma unroll
  for (int c = 0; c < 64; c++){
    float t = wb[c];
    #pragma unroll
    for (int k = 0; k < 5; k++) t += xv[k]*we[k*64 + c];
    a[c] = t;
  }
  float mean = 0.f;
  #pragma unroll
  for (int c = 0; c < 64; c++) mean += a[c];
  mean *= (1.f/64.f);
  float var = 0.f;
  #pragma unroll
  for (int c = 0; c < 64; c++){ float d = a[c]-mean; var += d*d; }
  var *= (1.f/64.f);
  float rstd = rsqrtf(var + 1e-5f);
  size_t rb = (size_t)n*64;
  #pragma unroll
  for (int c = 0; c < 64; c += 4){
    *(float4*)&h[rb + c] = make_float4(a[c], a[c+1], a[c+2], a[c+3]);
    ushort4 zv;
    zv.x = f2bf(fmaxf((a[c  ]-mean)*rstd*sg[c  ]+sb[c  ], 0.f));
    zv.y = f2bf(fmaxf((a[c+1]-mean)*rstd*sg[c+1]+sb[c+1], 0.f));
    zv.z = f2bf(fmaxf((a[c+2]-mean)*rstd*sg[c+2]+sb[c+2], 0.f));
    zv.w = f2bf(fmaxf((a[c+3]-mean)*rstd*sg[c+3]+sb[c+3], 0.f));
    *(ushort4*)&z[rb + c] = zv;
  }
}

// ---------------- GENConv softmax aggregation: u = z + agg [bf16 in/out] ----------------
__global__ __launch_bounds__(256) void k_agg(const u16* __restrict__ z, u16* __restrict__ u,
    const int* __restrict__ rowptr, const int* __restrict__ esrc,
    const float* __restrict__ tparam, int li){
  int lane = threadIdx.x & 63;
  int n = blockIdx.x*4 + (threadIdx.x >> 6);
  if (n >= NODES) return;
  float tp = tparam[li];
  int beg = rowptr[n], end = rowptr[n+1];
  float den = 0.f, num = 0.f;
  int e = beg;
  for (; e + 1 < end; e += 2){           // 2-way ILP on the gather chain
    int s0 = esrc[e], s1 = esrc[e+1];
    float m0 = bf2f(z[(size_t)s0*64 + lane]) + 1e-7f;
    float m1 = bf2f(z[(size_t)s1*64 + lane]) + 1e-7f;
    float e0 = __expf(m0*tp), e1 = __expf(m1*tp);
    den += e0 + e1; num += m0*e0 + m1*e1;
  }
  if (e < end){
    int s0 = esrc[e];
    float m0 = bf2f(z[(size_t)s0*64 + lane]) + 1e-7f;
    float e0 = __expf(m0*tp);
    den += e0; num += m0*e0;
  }
  float agg = num / fmaxf(den, 1e-16f);
  float zn = bf2f(z[(size_t)n*64 + lane]);
  u[(size_t)n*64 + lane] = f2bf(zn + agg);
}

// ---------------- MLP part A: act = relu(LN(u @ W1 + b1)) [u,act bf16] ----------------
// 4 threads per node; thread q computes hd[q*32 .. q*32+31].
__global__ __launch_bounds__(256) void k_mlpa(
    const u16* __restrict__ u, u16* __restrict__ act,
    const float* __restrict__ W1, const float* __restrict__ B1,
    const float* __restrict__ G1, const float* __restrict__ Q1){
  __shared__ __align__(16) float w1s[64*128];   // 32 KB
  __shared__ float su[64*65];                   // 16.6 KB u tile (64 nodes, fp32)
  __shared__ float cb1[128], cg1[128], cq1[128];
  int tid = threadIdx.x;
  for (int i = tid; i < 8192; i += 256) w1s[i] = W1[i];
  if (tid < 128){ cb1[tid] = B1[tid]; cg1[tid] = G1[tid]; cq1[tid] = Q1[tid]; }
  int base = blockIdx.x*64;
  int nval = NODES - base; if (nval > 64) nval = 64;
  if (nval < 0) nval = 0;
  const u32* up = (const u32*)u;                // bf16 pairs
  for (int i = tid; i < nval*32; i += 256){
    u32 pv = up[(size_t)base*32 + i];
    int node = i >> 5, cp = (i & 31) << 1;
    su[node*65 + cp    ] = bf2f((u16)(pv & 0xFFFFu));
    su[node*65 + cp + 1] = bf2f((u16)(pv >> 16));
  }
  __syncthreads();
  int nl = tid >> 2;          // local node 0..63
  int q  = tid & 3;           // quarter
  int n  = base + nl;
  if (nl >= nval) return;
  int jb = q*32;
  float hd[32];
  #pragma unroll
  for (int j = 0; j < 32; j++) hd[j] = cb1[jb + j];
  #pragma unroll 2
  for (int k = 0; k < 64; k++){
    float uk = su[nl*65 + k];
    const float4* wr = (const float4*)&w1s[k*128 + jb];
    #pragma unroll
    for (int j4 = 0; j4 < 8; j4++){
      float4 w = wr[j4];
      hd[j4*4  ] += uk*w.x; hd[j4*4+1] += uk*w.y;
      hd[j4*4+2] += uk*w.z; hd[j4*4+3] += uk*w.w;
    }
  }
  // LN over 128 (quad reduce)
  float s = 0.f;
  #pragma unroll
  for (int j = 0; j < 32; j++) s += hd[j];
  s += __shfl_xor(s, 1); s += __shfl_xor(s, 2);
  float mean = s*(1.f/128.f);
  float vs = 0.f;
  #pragma unroll
  for (int j = 0; j < 32; j++){ float d = hd[j]-mean; vs += d*d; }
  vs += __shfl_xor(vs, 1); vs += __shfl_xor(vs, 2);
  float rstd = rsqrtf(vs*(1.f/128.f) + 1e-5f);
  u16* arow = act + (size_t)n*128 + jb;
  #pragma unroll
  for (int j4 = 0; j4 < 8; j4++){
    ushort4 av;
    av.x = f2bf(fmaxf((hd[j4*4  ]-mean)*rstd*cg1[jb+j4*4  ] + cq1[jb+j4*4  ], 0.f));
    av.y = f2bf(fmaxf((hd[j4*4+1]-mean)*rstd*cg1[jb+j4*4+1] + cq1[jb+j4*4+1], 0.f));
    av.z = f2bf(fmaxf((hd[j4*4+2]-mean)*rstd*cg1[jb+j4*4+2] + cq1[jb+j4*4+2], 0.f));
    av.w = f2bf(fmaxf((hd[j4*4+3]-mean)*rstd*cg1[jb+j4*4+3] + cq1[jb+j4*4+3], 0.f));
    *(ushort4*)&arow[j4*4] = av;
  }
}

// ---------------- MLP part B: h += act @ W2 + b2 ; znext or pool [act,znext bf16] ----------------
// 4 threads per node; thread q computes out[q*16 .. q*16+15].
__global__ __launch_bounds__(256) void k_mlpb(
    const u16* __restrict__ act, float* __restrict__ h, u16* __restrict__ znext,
    float* __restrict__ pooled, const int* __restrict__ batch,
    const float* __restrict__ W2, const float* __restrict__ B2,
    const float* __restrict__ GN, const float* __restrict__ BN,
    int last){
  __shared__ __align__(16) float w2s[128*64];   // 32 KB
  __shared__ float cb2[64], cgn[64], cbn[64];
  int tid = threadIdx.x;
  for (int i = tid; i < 8192; i += 256) w2s[i] = W2[i];
  if (tid < 64){
    cb2[tid] = B2[tid];
    cgn[tid] = last ? 0.f : GN[tid];
    cbn[tid] = last ? 0.f : BN[tid];
  }
  __syncthreads();
  int gid = blockIdx.x*256 + tid;
  int n = gid >> 2;
  int q = gid & 3;
  if (n >= NODES) return;
  int cb = q*16;
  float out[16];
  #pragma unroll
  for (int c = 0; c < 16; c++) out[c] = cb2[cb + c];
  const uint4* arowv = (const uint4*)(act + (size_t)n*128);  // 16 x (8 bf16)
  #pragma unroll 2
  for (int m8 = 0; m8 < 16; m8++){
    uint4 av = arowv[m8];
    float aa[8];
    aa[0] = bf2f((u16)(av.x & 0xFFFFu)); aa[1] = bf2f((u16)(av.x >> 16));
    aa[2] = bf2f((u16)(av.y & 0xFFFFu)); aa[3] = bf2f((u16)(av.y >> 16));
    aa[4] = bf2f((u16)(av.z & 0xFFFFu)); aa[5] = bf2f((u16)(av.z >> 16));
    aa[6] = bf2f((u16)(av.w & 0xFFFFu)); aa[7] = bf2f((u16)(av.w >> 16));
    #pragma unroll
    for (int mm = 0; mm < 8; mm++){
      float aj = aa[mm];
      const float4* wr = (const float4*)&w2s[(m8*8 + mm)*64 + cb];
      #pragma unroll
      for (int c4 = 0; c4 < 4; c4++){
        float4 w = wr[c4];
        out[c4*4  ] += aj*w.x; out[c4*4+1] += aj*w.y;
        out[c4*4+2] += aj*w.z; out[c4*4+3] += aj*w.w;
      }
    }
  }
  size_t rb = (size_t)n*64 + cb;
  #pragma unroll
  for (int c4 = 0; c4 < 4; c4++){
    float4 hv = *(const float4*)&h[rb + c4*4];
    out[c4*4  ] += hv.x; out[c4*4+1] += hv.y;
    out[c4*4+2] += hv.z; out[c4*4+3] += hv.w;
  }
  if (!last){
    #pragma unroll
    for (int c4 = 0; c4 < 4; c4++)
      *(float4*)&h[rb + c4*4] = make_float4(out[c4*4], out[c4*4+1], out[c4*4+2], out[c4*4+3]);
    // next-layer z = relu(LN64(h_new)) -> bf16
    float s = 0.f;
    #pragma unroll
    for (int c = 0; c < 16; c++) s += out[c];
    s += __shfl_xor(s, 1); s += __shfl_xor(s, 2);
    float mean = s*(1.f/64.f);
    float vs = 0.f;
    #pragma unroll
    for (int c = 0; c < 16; c++){ float d = out[c]-mean; vs += d*d; }
    vs += __shfl_xor(vs, 1); vs += __shfl_xor(vs, 2);
    float rstd = rsqrtf(vs*(1.f/64.f) + 1e-5f);
    u32 pk[8];
    #pragma unroll
    for (int c2 = 0; c2 < 8; c2++){
      u16 lo = f2bf(fmaxf((out[c2*2  ]-mean)*rstd*cgn[cb+c2*2  ] + cbn[cb+c2*2  ], 0.f));
      u16 hi = f2bf(fmaxf((out[c2*2+1]-mean)*rstd*cgn[cb+c2*2+1] + cbn[cb+c2*2+1], 0.f));
      pk[c2] = (u32)lo | ((u32)hi << 16);
    }
    uint4* zp = (uint4*)&znext[rb];
    zp[0] = make_uint4(pk[0], pk[1], pk[2], pk[3]);
    zp[1] = make_uint4(pk[4], pk[5], pk[6], pk[7]);
  } else {
    int g = batch[n];
    #pragma unroll
    for (int c = 0; c < 16; c++) atomicAdd(&pooled[g*64 + cb + c], out[c]);
  }
}

// ---------------- pooled + var MLP -> t ; qkv for layer 0 ----------------
__global__ __launch_bounds__(128) void k_pool2(
    const float* __restrict__ pooled, const float* __restrict__ var_data,
    const float* __restrict__ v1W, const float* __restrict__ v1b,
    const float* __restrict__ v2W, const float* __restrict__ v2b,
    const float* __restrict__ v3W, const float* __restrict__ v3b,
    float* __restrict__ t, float* __restrict__ qkvout,
    const float* __restrict__ qW, const float* __restrict__ qb){
  __shared__ float vin[19], l1[16], l2[32], tr[128];
  int c = threadIdx.x, s = blockIdx.x;
  if (c < 19) vin[c] = var_data[s*19 + c];
  __syncthreads();
  if (c < 16){
    float a = v1b[c];
    for (int k = 0; k < 19; k++) a += vin[k]*v1W[k*16 + c];
    l1[c] = fmaxf(a, 0.f);
  }
  __syncthreads();
  if (c < 32){
    float a = v2b[c];
    for (int k = 0; k < 16; k++) a += l1[k]*v2W[k*32 + c];
    l2[c] = fmaxf(a, 0.f);
  }
  __syncthreads();
  float tv;
  if (c < 64) tv = pooled[s*64 + c];
  else {
    float a = v3b[c-64];
    for (int k = 0; k < 32; k++) a += l2[k]*v3W[k*64 + (c-64)];
    tv = a;
  }
  tr[c] = tv; t[s*128 + c] = tv;
  __syncthreads();
  #pragma unroll 1
  for (int r = 0; r < 3; r++){
    int col = r*128 + c;
    float a = qb[col];
    #pragma unroll 4
    for (int k = 0; k < 128; k++) a += tr[k]*qW[k*384 + col];
    qkvout[s*384 + col] = a;
  }
}

// ---------------- attention (8 heads, S=256, dh=16) ----------------
__global__ __launch_bounds__(256) void k_att(const float* __restrict__ qkv, float* __restrict__ oatt){
  __shared__ float kb[256*16];
  __shared__ float vb[256*16];
  int tid = threadIdx.x;
  int head = blockIdx.x >> 3;
  int tile = blockIdx.x & 7;
  int hb = head*16;
  for (int i = tid; i < 4096; i += 256){
    int s = i >> 4, d = i & 15;
    kb[i] = qkv[s*384 + 128 + hb + d];
    vb[i] = qkv[s*384 + 256 + hb + d];
  }
  __syncthreads();
  int row = tile*32 + (tid >> 3);
  int sub = tid & 7;
  float q[16];
  #pragma unroll
  for (int d = 0; d < 16; d++) q[d] = qkv[row*384 + hb + d];
  float sc[32];
  int k0 = sub*32;
  #pragma unroll
  for (int kk = 0; kk < 32; kk++){
    const float* kr = &kb[(k0+kk)*16];
    float s = 0.f;
    #pragma unroll
    for (int d = 0; d < 16; d++) s += q[d]*kr[d];
    sc[kk] = s*0.25f;
  }
  float m = -1e30f;
  #pragma unroll
  for (int kk = 0; kk < 32; kk++) m = fmaxf(m, sc[kk]);
  m = fmaxf(m, __shfl_xor(m, 1)); m = fmaxf(m, __shfl_xor(m, 2)); m = fmaxf(m, __shfl_xor(m, 4));
  float sum = 0.f;
  #pragma unroll
  for (int kk = 0; kk < 32; kk++){ sc[kk] = __expf(sc[kk]-m); sum += sc[kk]; }
  sum += __shfl_xor(sum, 1); sum += __shfl_xor(sum, 2); sum += __shfl_xor(sum, 4);
  float o[16];
  #pragma unroll
  for (int d = 0; d < 16; d++) o[d] = 0.f;
  #pragma unroll
  for (int kk = 0; kk < 32; kk++){
    const float* vr = &vb[(k0+kk)*16];
    float p = sc[kk];
    #pragma unroll
    for (int d = 0; d < 16; d++) o[d] += p*vr[d];
  }
  float inv = 1.f/sum;
  #pragma unroll
  for (int d = 0; d < 16; d++){
    float tv = o[d];
    tv += __shfl_xor(tv, 1); tv += __shfl_xor(tv, 2); tv += __shfl_xor(tv, 4);
    if (sub == 0) oatt[row*128 + hb + d] = tv*inv;
  }
}

// ---------------- encoder row-local: oproj+LN1+FF+LN2 (+ next qkv / head) ----------------
__global__ __launch_bounds__(128) void k_row(
    const float* __restrict__ oatt, float* __restrict__ t, float* __restrict__ qkvout,
    const float* __restrict__ outW, const float* __restrict__ outb,
    const float* __restrict__ l1g, const float* __restrict__ l1b,
    const float* __restrict__ f1W, const float* __restrict__ f1b,
    const float* __restrict__ f2W, const float* __restrict__ f2b,
    const float* __restrict__ l2g, const float* __restrict__ l2b,
    const float* __restrict__ qW, const float* __restrict__ qb,
    const float* __restrict__ hW, const float* __restrict__ hb2,
    float* __restrict__ dout, int last){
  __shared__ float so[128], st[128], s1[128], sf[128];
  __shared__ float red[2];
  int c = threadIdx.x, s = blockIdx.x;
  so[c] = oatt[s*128 + c];
  st[c] = t[s*128 + c];
  __syncthreads();
  float acc = outb[c];
  #pragma unroll 4
  for (int k = 0; k < 128; k++) acc += so[k]*outW[k*128 + c];
  acc += st[c];
  float mean = blockSum128(acc, red)*(1.f/128.f);
  float d0 = acc - mean;
  float var = blockSum128(d0*d0, red)*(1.f/128.f);
  float t1 = d0*rsqrtf(var + 1e-5f)*l1g[c] + l1b[c];
  s1[c] = t1;
  __syncthreads();
  float f = f1b[c];
  #pragma unroll 4
  for (int k = 0; k < 128; k++) f += s1[k]*f1W[k*128 + c];
  f = 0.5f*f*(1.f + erff(f*0.70710678118654752f));
  sf[c] = f;
  __syncthreads();
  float g = f2b[c];
  #pragma unroll 4
  for (int k = 0; k < 128; k++) g += sf[k]*f2W[k*128 + c];
  g += t1;
  float mean2 = blockSum128(g, red)*(1.f/128.f);
  float d2 = g - mean2;
  float var2 = blockSum128(d2*d2, red)*(1.f/128.f);
  float t2 = d2*rsqrtf(var2 + 1e-5f)*l2g[c] + l2b[c];
  t[s*128 + c] = t2;
  __syncthreads();
  s1[c] = t2;
  __syncthreads();
  if (!last){
    #pragma unroll 1
    for (int r = 0; r < 3; r++){
      int col = r*128 + c;
      float a = qb[col];
      #pragma unroll 4
      for (int k = 0; k < 128; k++) a += s1[k]*qW[k*384 + col];
      qkvout[s*384 + col] = a;
    }
  } else {
    if (c < 2){
      float a = hb2[c];
      for (int k = 0; k < 128; k++) a += s1[k]*hW[k*2 + c];
      dout[s*2 + c] = a;
    }
  }
}

// ---------------- host ----------------
extern "C" void kernel_launch(void* const* d_in, const int* in_sizes, int n_in,
                              void* d_out, int out_size, void* d_ws, size_t ws_size,
                              hipStream_t stream){
  const float* x       = (const float*)d_in[0];
  const int*   ei      = (const int*)  d_in[1];
  const int*   batch   = (const int*)  d_in[2];
  const float* var_d   = (const float*)d_in[3];
  const float* encW    = (const float*)d_in[4];
  const float* encb    = (const float*)d_in[5];
  const float* ln_g    = (const float*)d_in[6];
  const float* ln_b    = (const float*)d_in[7];
  const float* tparam  = (const float*)d_in[8];
  const float* m1W     = (const float*)d_in[9];
  const float* m1b     = (const float*)d_in[10];
  const float* mng     = (const float*)d_in[11];
  const float* mnb     = (const float*)d_in[12];
  const float* m2W     = (const float*)d_in[13];
  const float* m2b     = (const float*)d_in[14];
  const float* v1W     = (const float*)d_in[15];
  const float* v1b     = (const float*)d_in[16];
  const float* v2W     = (const float*)d_in[17];
  const float* v2b     = (const float*)d_in[18];
  const float* v3W     = (const float*)d_in[19];
  const float* v3b     = (const float*)d_in[20];
  const float* qkvW    = (const float*)d_in[21];
  const float* qkvB    = (const float*)d_in[22];
  const float* outW    = (const float*)d_in[23];
  const float* outb    = (const float*)d_in[24];
  const float* l1g     = (const float*)d_in[25];
  const float* l1b     = (const float*)d_in[26];
  const float* f1W     = (const float*)d_in[27];
  const float* f1b     = (const float*)d_in[28];
  const float* f2W     = (const float*)d_in[29];
  const float* f2b     = (const float*)d_in[30];
  const float* l2g     = (const float*)d_in[31];
  const float* l2b     = (const float*)d_in[32];
  const float* headW   = (const float*)d_in[33];
  const float* headB   = (const float*)d_in[34];
  float* dout = (float*)d_out;

  char* wsb = (char*)d_ws;
  size_t off = 0;
  auto nxt = [&](size_t bytes)->void*{
    void* p = wsb + off;
    off += (bytes + 255) & ~(size_t)255;
    return p;
  };
  float* h      = (float*)nxt((size_t)NODES*64*4);
  u16*   z      = (u16*)  nxt((size_t)NODES*64*2);
  u16*   u      = (u16*)  nxt((size_t)NODES*64*2);
  u16*   act    = (u16*)  nxt((size_t)NODES*128*2);
  int*   rowptr = (int*)  nxt((size_t)(NODES+1)*4);
  int*   cursor = (int*)  nxt((size_t)NODES*4);
  int*   counts = (int*)  nxt((size_t)NODES*4);
  int*   bsums  = (int*)  nxt(64*4);
  int*   boffs  = (int*)  nxt(64*4);
  int*   esrc   = (int*)  nxt((size_t)EDGES*4);
  float* pooled = (float*)nxt((size_t)NG*64*4);
  float* tbuf   = (float*)nxt((size_t)NG*128*4);
  float* qkvb   = (float*)nxt((size_t)NG*384*4);
  float* oatt   = (float*)nxt((size_t)NG*128*4);

  const int* srcp = ei;
  const int* dstp = ei + EDGES;

  k_zero_i <<<391, 256, 0, stream>>>(counts, NODES);
  k_hist   <<<4688, 256, 0, stream>>>(dstp, counts);
  k_scan1  <<<49, 256, 0, stream>>>(counts, rowptr, bsums);
  k_scan2  <<<1, 64, 0, stream>>>(bsums, boffs, 49);
  k_scan3  <<<391, 256, 0, stream>>>(rowptr, cursor, boffs);
  k_scatter<<<4688, 256, 0, stream>>>(srcp, dstp, cursor, esrc);
  k_zero_f <<<64, 256, 0, stream>>>(pooled, NG*64);
  k_enc    <<<391, 256, 0, stream>>>(x, encW, encb, ln_g, ln_b, h, z);

  for (int i = 0; i < 6; i++){
    int last = (i == 5);
    k_agg <<<25000, 256, 0, stream>>>(z, u, rowptr, esrc, tparam, i);
    k_mlpa<<<1563, 256, 0, stream>>>(u, act,
        m1W + i*8192, m1b + i*128, mng + i*128, mnb + i*128);
    k_mlpb<<<1563, 256, 0, stream>>>(act, h, z, pooled, batch,
        m2W + i*8192, m2b + i*64,
        ln_g + (last ? 0 : (i+1)*64), ln_b + (last ? 0 : (i+1)*64), last);
  }

  k_pool2<<<NG, 128, 0, stream>>>(pooled, var_d, v1W, v1b, v2W, v2b, v3W, v3b,
                                  tbuf, qkvb, qkvW, qkvB);

  for (int i = 0; i < 6; i++){
    int last = (i == 5);
    k_att<<<64, 256, 0, stream>>>(qkvb, oatt);
    k_row<<<NG, 128, 0, stream>>>(oatt, tbuf, qkvb,
        outW + i*16384, outb + i*128, l1g + i*128, l1b + i*128,
        f1W + i*16384, f1b + i*128, f2W + i*16384, f2b + i*128,
        l2g + i*128, l2b + i*128,
        qkvW + (size_t)(last ? 0 : (i+1))*49152, qkvB + (last ? 0 : (i+1))*384,
        headW, headB, dout, last);
  }
}